// Round 1
// baseline (359.065 us; speedup 1.0000x reference)
//
#include <hip/hip_runtime.h>

// Match numpy f32 semantics: no FMA contraction anywhere in this TU.
#pragma clang fp contract(off)

#define VWD 96
#define NVERT 2048
#define NFAC 512
#define NBATCH 8
#define NSLAB 3456          // 12 x 12 x 24 slabs of 8x8x4 voxels
#define RECF 16             // floats per facet body record
#define CULC 26             // cull components (SoA): bbox 6 + 4 planes x 4 + 4 containment deltas

// SoA cull addressing: component c, batch b, facet f
#define CUL(c, b, f) cul[(size_t)(c) * (NBATCH * NFAC) + (size_t)(b) * NFAC + (f)]

// ---------------------------------------------------------------------------
// Kernel 1: per-batch facet precompute, ordered by |det| descending via a
// ONE-BARRIER rank sort. Fully scalarized. Body records SIGN-FOLDED: det<0 =>
// negate A,det (IEEE negation commutes exactly through mul/add/div, so
// n'/det' == n/det bit-for-bit).
//   body[b][s][16] : det,v3x,v3y,v3z, A00..A22, dhi, mhi, pad
//   dhi = det*(1-1e-5) - 1e-25   (definite-inside upper bound on sum)
//   mhi = det*(1+1e-5) + 1e-25   (maybe-inside upper bound; +-1e-25 guards
//                                 det=0 degenerate facets: ref l=NaN=outside)
// New: per-plane containment delta D_i = -(M + 2E + 2e-3). A slab whose
// incremental plane dot satisfies d_i <= D_i for all 4 planes lies entirely
// inside the tet with plane margin >= 2e-3 - eval_err (~1.5e-4), which in
// barycentric units is (2e-3 - err)/|det| >> ref's lam rounding ~4e-5/|det|
// (plane normal and adjugate row are both 2*face-area => s_i(v_i) == |det|,
// so |det| cancels). Degenerate facets cannot pass (max interior plane
// distance ~= 0 < margin).
// ---------------------------------------------------------------------------
__global__ __launch_bounds__(512) void precompute_kernel(
    const float* __restrict__ vertices,
    const int*   __restrict__ facets,
    float*       __restrict__ cul,
    float*       __restrict__ body,
    unsigned*    __restrict__ scnt)
{
    __shared__ unsigned skey[NFAC];
    const int b = blockIdx.x;
    const int j = threadIdx.x;          // one facet per thread
    if (b == 0 && j == 0) scnt[0] = 0u; // reset straggler counter each launch
    const float* vb = vertices + (size_t)b * NVERT * 3;

    int4 fi = ((const int4*)facets)[b * NFAC + j];
    float x0 = vb[3*fi.x+0], y0 = vb[3*fi.x+1], z0 = vb[3*fi.x+2];
    float x1 = vb[3*fi.y+0], y1 = vb[3*fi.y+1], z1 = vb[3*fi.y+2];
    float x2 = vb[3*fi.z+0], y2 = vb[3*fi.z+1], z2 = vb[3*fi.z+2];
    float x3 = vb[3*fi.w+0], y3 = vb[3*fi.w+1], z3 = vb[3*fi.w+2];
    float a  = x0-x3, bb = x1-x3, c  = x2-x3;
    float d  = y0-y3, e  = y1-y3, f  = y2-y3;
    float g  = z0-z3, h  = z1-z3, ii = z2-z3;
    float A00 = e*ii - f*h,  A01 = c*h  - bb*ii, A02 = bb*f - c*e;
    float A10 = f*g  - d*ii, A11 = a*ii - c*g,   A12 = c*d  - a*f;
    float A20 = d*h  - e*g,  A21 = bb*g - a*h,   A22 = a*e  - bb*d;
    float det = a*(e*ii - f*h) - bb*(d*ii - f*g) + c*(d*h - e*g);
    if (det < 0.0f) {   // sign-fold (exact)
        det = -det;
        A00 = -A00; A01 = -A01; A02 = -A02;
        A10 = -A10; A11 = -A11; A12 = -A12;
        A20 = -A20; A21 = -A21; A22 = -A22;
    }
    unsigned myk = ~__float_as_uint(det);   // ascending key == descending |det|
    skey[j] = myk;
    __syncthreads();

    // rank = #{k : key_k < myk or (key_k == myk and k < j)}  -> unique slot
    int rank = 0;
    const uint4* sk4 = (const uint4*)skey;
    for (int k0 = 0; k0 < NFAC; k0 += 4) {
        uint4 kk = sk4[k0 >> 2];
        rank += (kk.x < myk) + ((kk.x == myk) & (k0 + 0 < j));
        rank += (kk.y < myk) + ((kk.y == myk) & (k0 + 1 < j));
        rank += (kk.z < myk) + ((kk.z == myk) & (k0 + 2 < j));
        rank += (kk.w < myk) + ((kk.w == myk) & (k0 + 3 < j));
    }

    CUL(0, b, rank) = fminf(fminf(x0,x1),fminf(x2,x3)) - 1e-4f;
    CUL(1, b, rank) = fminf(fminf(y0,y1),fminf(y2,y3)) - 1e-4f;
    CUL(2, b, rank) = fminf(fminf(z0,z1),fminf(z2,z3)) - 1e-4f;
    CUL(3, b, rank) = fmaxf(fmaxf(x0,x1),fmaxf(x2,x3)) + 1e-4f;
    CUL(4, b, rank) = fmaxf(fmaxf(y0,y1),fmaxf(y2,y3)) + 1e-4f;
    CUL(5, b, rank) = fmaxf(fmaxf(z0,z1),fmaxf(z2,z3)) + 1e-4f;

    // 4 outward face planes, margin-inflated, slab half-extents folded:
    // overlap test becomes  dot(n, slab_center) - rhs <= 0   (conservative).
    // containment test:     dot(n, slab_center) - rhs <= D   (definite).
    const float HX = 7.0f/96.0f, HZ = 3.0f/96.0f;
    auto plane = [&](float pax, float pay, float paz,
                     float pbx, float pby, float pbz,
                     float pcx, float pcy, float pcz,
                     float pox, float poy, float poz, int base, int pi) {
        float e1x = pbx-pax, e1y = pby-pay, e1z = pbz-paz;
        float e2x = pcx-pax, e2y = pcy-pay, e2z = pcz-paz;
        float nx = e1y*e2z - e1z*e2y;
        float ny = e1z*e2x - e1x*e2z;
        float nz = e1x*e2y - e1y*e2x;
        float sdot = nx*(pox-pax) + ny*(poy-pay) + nz*(poz-paz);
        if (sdot > 0.0f) { nx=-nx; ny=-ny; nz=-nz; sdot=-sdot; }
        float dpl = nx*pax + ny*pay + nz*paz;
        float n1s = fabsf(nx)+fabsf(ny)+fabsf(nz);
        float M = 1e-4f*(-sdot) + 1e-4f*n1s + 1e-4f;
        float E = fabsf(nx)*HX + fabsf(ny)*HX + fabsf(nz)*HZ;
        float rhs = dpl + M + E;
        CUL(base+0, b, rank) = nx;
        CUL(base+1, b, rank) = ny;
        CUL(base+2, b, rank) = nz;
        CUL(base+3, b, rank) = rhs;
        CUL(22+pi, b, rank) = -(M + 2.0f*E + 2e-3f);   // containment delta
    };
    plane(x1,y1,z1, x2,y2,z2, x3,y3,z3, x0,y0,z0, 6, 0);    // opposite v0
    plane(x0,y0,z0, x2,y2,z2, x3,y3,z3, x1,y1,z1, 10, 1);   // opposite v1
    plane(x0,y0,z0, x1,y1,z1, x3,y3,z3, x2,y2,z2, 14, 2);   // opposite v2
    plane(x0,y0,z0, x1,y1,z1, x2,y2,z2, x3,y3,z3, 18, 3);   // opposite v3

    float* bo = body + ((size_t)b * NFAC + rank) * RECF;
    bo[0]  = det; bo[1]  = x3;  bo[2]  = y3;  bo[3]  = z3;
    bo[4]  = A00; bo[5]  = A01; bo[6]  = A02; bo[7]  = A10;
    bo[8]  = A11; bo[9]  = A12; bo[10] = A20; bo[11] = A21;
    bo[12] = A22;
    bo[13] = det * (1.0f - 1e-5f) - 1e-25f;   // dhi
    bo[14] = det * (1.0f + 1e-5f) + 1e-25f;   // mhi
    bo[15] = 0.0f;
}

// ---------------------------------------------------------------------------
// Kernel 2: per-slab 512-bit facet mask + per-slab "fully contained" flag.
// One block per (batch, x-y column); facet-per-lane, cull record loaded ONCE
// (SoA, coalesced), 24 z-slabs via incremental plane dots (error ~1e-4 <<
// margins folded into rhs / delta).
// ---------------------------------------------------------------------------
__global__ __launch_bounds__(512) void mask_kernel(
    const float* __restrict__ cul,
    unsigned long long* __restrict__ masks,
    unsigned* __restrict__ fullmask)
{
    __shared__ unsigned fullbits;
    const int col = blockIdx.x;           // 0..143 = sx*12+sy
    const int b   = blockIdx.y;
    const int f   = threadIdx.x;          // facet (sorted order)
    const int w   = threadIdx.x >> 6;
    if (threadIdx.x == 0) fullbits = 0u;
    __syncthreads();
    float bminx=CUL(0,b,f), bminy=CUL(1,b,f), bminz=CUL(2,b,f);
    float bmaxx=CUL(3,b,f), bmaxy=CUL(4,b,f), bmaxz=CUL(5,b,f);
    float n0x=CUL(6,b,f),  n0y=CUL(7,b,f),  n0z=CUL(8,b,f),  r0=CUL(9,b,f);
    float n1x=CUL(10,b,f), n1y=CUL(11,b,f), n1z=CUL(12,b,f), r1=CUL(13,b,f);
    float n2x=CUL(14,b,f), n2y=CUL(15,b,f), n2z=CUL(16,b,f), r2=CUL(17,b,f);
    float n3x=CUL(18,b,f), n3y=CUL(19,b,f), n3z=CUL(20,b,f), r3=CUL(21,b,f);
    float D0=CUL(22,b,f), D1=CUL(23,b,f), D2=CUL(24,b,f), D3=CUL(25,b,f);

    const int sx = col / 12, sy = col % 12;
    const float cx = (float)(16*sx + 8 - VWD) / 96.0f;
    const float cy = (float)(16*sy + 8 - VWD) / 96.0f;
    const float colminx = (float)(16*sx + 1  - VWD) / 96.0f;
    const float colmaxx = (float)(16*sx + 15 - VWD) / 96.0f;
    const float colminy = (float)(16*sy + 1  - VWD) / 96.0f;
    const float colmaxy = (float)(16*sy + 15 - VWD) / 96.0f;
    const bool ovxy = (bminx <= colmaxx) & (bmaxx >= colminx) &
                      (bminy <= colmaxy) & (bmaxy >= colminy);

    const float cz0   = (float)(4 - VWD) / 96.0f;   // z-center of slab sz=0
    const float stepc = 8.0f / 96.0f;
    float d0 = n0x*cx + n0y*cy + n0z*cz0 - r0;  float s0 = n0z*stepc;
    float d1 = n1x*cx + n1y*cy + n1z*cz0 - r1;  float s1 = n1z*stepc;
    float d2 = n2x*cx + n2y*cy + n2z*cz0 - r2;  float s2 = n2z*stepc;
    float d3 = n3x*cx + n3y*cy + n3z*cz0 - r3;  float s3 = n3z*stepc;
    float zlo = (float)(1 - VWD) / 96.0f;
    float zhi = (float)(7 - VWD) / 96.0f;

    unsigned fullw = 0u;
    unsigned long long* mp = masks + ((size_t)b * NSLAB + (size_t)col * 24) * 8 + w;
#pragma unroll 4
    for (int sz = 0; sz < 24; ++sz) {
        bool ov = ovxy & (bminz <= zhi) & (bmaxz >= zlo) &
                  (d0 <= 0.0f) & (d1 <= 0.0f) & (d2 <= 0.0f) & (d3 <= 0.0f);
        bool fullv = (d0 <= D0) & (d1 <= D1) & (d2 <= D2) & (d3 <= D3);
        unsigned long long bal = __ballot((int)ov);
        if ((threadIdx.x & 63) == 0) mp[(size_t)sz * 8] = bal;
        if (__ballot((int)fullv) != 0ull) fullw |= (1u << sz);
        d0 += s0; d1 += s1; d2 += s2; d3 += s3;
        zlo += stepc; zhi += stepc;
    }
    if ((threadIdx.x & 63) == 0 && fullw) atomicOr(&fullbits, fullw);
    __syncthreads();
    if (threadIdx.x == 0) fullmask[b * 144 + col] = fullbits;
}

// ---------------------------------------------------------------------------
// Per-candidate exact test (shared by pass 1 and the straggler pass).
// Numerators bit-identical to ref; exact l_i>=0 sign test; det-relative shell
// on the sum; per-lane 4-bit `need` mask so only ONE __any branch per
// candidate guards the (rare) exact-division path.
// ---------------------------------------------------------------------------
__device__ __forceinline__ void facet_test(
    const float* __restrict__ bo,
    float px, float py, float pz0, float pz1, float pz2, float pz3,
    unsigned& fnd)
{
    float det = bo[0], v3x = bo[1], v3y = bo[2], v3z = bo[3];
    float A00 = bo[4],  A01 = bo[5],  A02 = bo[6],  A10 = bo[7];
    float A11 = bo[8],  A12 = bo[9],  A20 = bo[10], A21 = bo[11];
    float A22 = bo[12], dhi = bo[13], mhi = bo[14];
    float dx = px - v3x, dy = py - v3y;
    // ref-exact partials (left-assoc, contract off)
    float p0 = A00*dx + A01*dy;
    float p1 = A10*dx + A11*dy;
    float p2 = A20*dx + A21*dy;
    float dzk0 = pz0 - v3z, dzk1 = pz1 - v3z;
    float dzk2 = pz2 - v3z, dzk3 = pz3 - v3z;
    unsigned need = 0u;   // bit k: lane in shell, must run exact path
#pragma unroll
    for (int k = 0; k < 4; ++k) {
        float dzk = (k == 0) ? dzk0 : (k == 1) ? dzk1
                  : (k == 2) ? dzk2 : dzk3;
        // n_i bit-identical to reference's numerators
        float n0 = p0 + A02*dzk;
        float n1 = p1 + A12*dzk;
        float n2 = p2 + A22*dzk;
        float sm = (n0 + n1) + n2;
        float mn = fminf(fminf(n0, n1), n2);   // v_min3_f32
        bool ge0 = (mn >= 0.0f);               // EXACT l_i>=0 test
        bool def = ge0 & (sm <= dhi);
        bool may = ge0 & (sm <= mhi);
        if (may & !def & !((fnd >> k) & 1u)) need |= (1u << k);
        if (def) fnd |= (1u << k);
    }
    if (__any(need != 0u)) {
        // exact path (rare): ref's divisions + final test, per k
#pragma unroll
        for (int k = 0; k < 4; ++k) {
            float dzk = (k == 0) ? dzk0 : (k == 1) ? dzk1
                      : (k == 2) ? dzk2 : dzk3;
            float n0 = p0 + A02*dzk;
            float n1 = p1 + A12*dzk;
            float n2 = p2 + A22*dzk;
            float l0 = n0 / det;
            float l1 = n1 / det;
            float l2 = n2 / det;
            float l3 = 1.0f - ((l0 + l1) + l2);
            bool inside = (l0 >= 0.0f) & (l0 <= 1.0f) &
                          (l1 >= 0.0f) & (l1 <= 1.0f) &
                          (l2 >= 0.0f) & (l2 <= 1.0f) &
                          (l3 >= 0.0f) & (l3 <= 1.0f);
            if (((need >> k) & 1u) & inside) fnd |= (1u << k);
        }
    }
}

// ---------------------------------------------------------------------------
// Kernel 3 (pass 1): 2-WAVE blocks. New vs previous round:
//  - fully-contained slabs (fullmask bit) write 1s with NO scanning;
//  - candidate scan capped at mask words 0..1 (128 biggest-|det| facets);
//    incomplete waves with work remaining in words 2..7 write their partial
//    result and push (b,slab) to a global straggler list for pass 2.
// This bounds the per-wave pole at 128 candidates (was 512 -> ~40us tail).
// ---------------------------------------------------------------------------
__global__ __launch_bounds__(128) void voxelize_kernel(
    const float*              __restrict__ body,
    const unsigned long long* __restrict__ masks,
    const unsigned*           __restrict__ fullmask,
    float*                    __restrict__ out,
    unsigned*                 __restrict__ scnt,
    unsigned short*           __restrict__ slist)
{
    const int b    = blockIdx.y;
    const int wave = threadIdx.x >> 6;
    const int lane = threadIdx.x & 63;
    const int slab = blockIdx.x * 2 + wave;          // 0 .. 3455
    const int sz = slab % 24;
    const int col = slab / 24;
    const int sy = col % 12;
    const int sx = slab / 288;
    const int ix  = sx*8 + (lane >> 3);
    const int iy  = sy*8 + (lane & 7);
    const int iz0 = sz*4;

    const float px  = (float)(2*ix + 1 - VWD) / 96.0f;
    const float py  = (float)(2*iy + 1 - VWD) / 96.0f;
    const float pz0 = (float)(2*(iz0+0) + 1 - VWD) / 96.0f;
    const float pz1 = (float)(2*(iz0+1) + 1 - VWD) / 96.0f;
    const float pz2 = (float)(2*(iz0+2) + 1 - VWD) / 96.0f;
    const float pz3 = (float)(2*(iz0+3) + 1 - VWD) / 96.0f;

    unsigned fnd = 0u;   // bit k = voxel (ix,iy,iz0+k) found

    // fully-contained slab: convexity => every voxel definitely inside.
    if ((fullmask[b * 144 + col] >> sz) & 1u) { fnd = 15u; goto done; }

    {
        const unsigned long long* mp = masks + ((size_t)b * NSLAB + slab) * 8;
        const float* bb = body + (size_t)b * NFAC * RECF;
#pragma unroll
        for (int w = 0; w < 2; ++w) {
            unsigned long long m = mp[w];   // wave-uniform -> SGPR
            while (m) {
                int bit = __builtin_ctzll(m);
                m &= m - 1;
                int f = __builtin_amdgcn_readfirstlane(w * 64 + bit);
                facet_test(bb + f * RECF, px, py, pz0, pz1, pz2, pz3, fnd);
                if (__all(fnd == 15u)) goto done;
            }
        }
        // cap reached: defer remaining words to the straggler pass
        unsigned long long rem = mp[2] | mp[3] | mp[4] | mp[5] | mp[6] | mp[7];
        if (rem != 0ull && !__all(fnd == 15u)) {
            if (lane == 0) {
                unsigned idx = atomicAdd(scnt, 1u);
                slist[idx] = (unsigned short)(b * NSLAB + slab);
            }
        }
    }
done:
    float4 v;
    v.x = (fnd & 1u) ? 1.0f : 0.0f;
    v.y = (fnd & 2u) ? 1.0f : 0.0f;
    v.z = (fnd & 4u) ? 1.0f : 0.0f;
    v.w = (fnd & 8u) ? 1.0f : 0.0f;
    *(float4*)&out[(size_t)b*(VWD*VWD*VWD) + (size_t)ix*(VWD*VWD) + iy*VWD + iz0] = v;
}

// ---------------------------------------------------------------------------
// Kernel 4 (pass 2, stragglers only): 6 waves per block, wave w scans mask
// word 2+w. Seeded with pass-1 partial result from `out`; per-lane union in
// LDS gives cross-wave early exit; final result = seed | all waves' finds.
// Pole per straggler slab drops from 384 serial candidates to 64.
// ---------------------------------------------------------------------------
__global__ __launch_bounds__(384) void voxelize_fix_kernel(
    const float*              __restrict__ body,
    const unsigned long long* __restrict__ masks,
    float*                    __restrict__ out,
    const unsigned*           __restrict__ scnt,
    const unsigned short*     __restrict__ slist)
{
    __shared__ unsigned fl[64];
    const int wave = threadIdx.x >> 6;          // 0..5 -> words 2..7
    const int lane = threadIdx.x & 63;
    const unsigned count = *scnt;

    for (unsigned e = blockIdx.x; e < count; e += gridDim.x) {
        const int v    = (int)slist[e];
        const int b    = v / NSLAB;
        const int slab = v % NSLAB;
        const int sz = slab % 24;
        const int sy = (slab / 24) % 12;
        const int sx = slab / 288;
        const int ix  = sx*8 + (lane >> 3);
        const int iy  = sy*8 + (lane & 7);
        const int iz0 = sz*4;
        const float px  = (float)(2*ix + 1 - VWD) / 96.0f;
        const float py  = (float)(2*iy + 1 - VWD) / 96.0f;
        const float pz0 = (float)(2*(iz0+0) + 1 - VWD) / 96.0f;
        const float pz1 = (float)(2*(iz0+1) + 1 - VWD) / 96.0f;
        const float pz2 = (float)(2*(iz0+2) + 1 - VWD) / 96.0f;
        const float pz3 = (float)(2*(iz0+3) + 1 - VWD) / 96.0f;
        float* op = &out[(size_t)b*(VWD*VWD*VWD) + (size_t)ix*(VWD*VWD) + iy*VWD + iz0];

        __syncthreads();                  // LDS reuse guard (prev iteration)
        if (threadIdx.x < 64) {
            float4 o = *(const float4*)op;
            fl[threadIdx.x] = (o.x != 0.0f ? 1u : 0u) | (o.y != 0.0f ? 2u : 0u)
                            | (o.z != 0.0f ? 4u : 0u) | (o.w != 0.0f ? 8u : 0u);
        }
        __syncthreads();

        unsigned fnd = fl[lane];          // seed from pass-1 partial
        unsigned pub = fnd;
        const unsigned long long* mp = masks + ((size_t)b * NSLAB + slab) * 8;
        const float* bb = body + (size_t)b * NFAC * RECF;
        unsigned long long m = mp[2 + wave];
        while (m) {
            int bit = __builtin_ctzll(m);
            m &= m - 1;
            int f = __builtin_amdgcn_readfirstlane((2 + wave) * 64 + bit);
            facet_test(bb + f * RECF, px, py, pz0, pz1, pz2, pz3, fnd);
            if (fnd != pub) { atomicOr(&fl[lane], fnd); pub = fnd; }
            fnd |= fl[lane];              // cross-wave union (monotonic)
            if (__all(fnd == 15u)) break;
        }
        if (fnd != pub) atomicOr(&fl[lane], fnd);
        __syncthreads();
        if (threadIdx.x < 64) {
            unsigned u = fl[threadIdx.x];
            float4 r;
            r.x = (u & 1u) ? 1.0f : 0.0f;
            r.y = (u & 2u) ? 1.0f : 0.0f;
            r.z = (u & 4u) ? 1.0f : 0.0f;
            r.w = (u & 8u) ? 1.0f : 0.0f;
            *(float4*)op = r;
        }
    }
}

extern "C" void kernel_launch(void* const* d_in, const int* in_sizes, int n_in,
                              void* d_out, int out_size, void* d_ws, size_t ws_size,
                              hipStream_t stream) {
    const float* vertices = (const float*)d_in[0];   // (8, 2048, 3) f32
    const int*   facets   = (const int*)d_in[1];     // (8, 512, 4) int
    float*       out      = (float*)d_out;           // (8, 96, 96, 96) f32

    // d_ws layout:
    //   cul SoA     26*8*512*4 = 425984   @ 0
    //   body        8*512*16*4 = 262144   @ 425984
    //   masks       8*3456*8*8 = 1769472  @ 688128
    //   fullmask    8*144*4    = 4608     @ 2457600
    //   scnt        4 (padded)            @ 2462208
    //   slist       27648*2    = 55296    @ 2462272   (end ~2.52 MB)
    float* cul  = (float*)d_ws;
    float* body = (float*)((char*)d_ws + 425984);
    unsigned long long* msk = (unsigned long long*)((char*)d_ws + 688128);
    unsigned* fullmask = (unsigned*)((char*)d_ws + 2457600);
    unsigned* scnt     = (unsigned*)((char*)d_ws + 2462208);
    unsigned short* slist = (unsigned short*)((char*)d_ws + 2462272);

    precompute_kernel<<<NBATCH, 512, 0, stream>>>(vertices, facets, cul, body, scnt);
    mask_kernel<<<dim3(144, NBATCH), 512, 0, stream>>>(cul, msk, fullmask);
    dim3 grid(NSLAB / 2, NBATCH);   // 1728 blocks x 2 waves = 3456 slabs/batch
    voxelize_kernel<<<grid, 128, 0, stream>>>(body, msk, fullmask, out, scnt, slist);
    voxelize_fix_kernel<<<1024, 384, 0, stream>>>(body, msk, out, scnt, slist);
}

// Round 2
// 182.358 us; speedup vs baseline: 1.9690x; 1.9690x over previous
//
#include <hip/hip_runtime.h>

// Match numpy f32 semantics: no FMA contraction anywhere in this TU.
#pragma clang fp contract(off)

#define VWD 96
#define NVERT 2048
#define NFAC 512
#define NBATCH 8
#define NSLAB 3456          // 12 x 12 x 24 slabs of 8x8x4 voxels
#define RECF 16             // floats per facet body record
#define CULC 26             // cull components (SoA): bbox 6 + 4 planes x 4 + 4 containment deltas

// SoA cull addressing: component c, batch b, facet f
#define CUL(c, b, f) cul[(size_t)(c) * (NBATCH * NFAC) + (size_t)(b) * NFAC + (f)]

// ---------------------------------------------------------------------------
// Kernel 1: per-batch facet precompute, ordered by |det| descending via a
// ONE-BARRIER rank sort. Fully scalarized. Body records SIGN-FOLDED: det<0 =>
// negate A,det (IEEE negation commutes exactly through mul/add/div, so
// n'/det' == n/det bit-for-bit).
//   body[b][s][16] : det,v3x,v3y,v3z, A00..A22, dhi, mhi, pad
//   dhi = det*(1-1e-5) - 1e-25   (definite-inside upper bound on sum)
//   mhi = det*(1+1e-5) + 1e-25   (maybe-inside upper bound; +-1e-25 guards
//                                 det=0 degenerate facets: ref l=NaN=outside)
// Per-plane containment delta D_i = -(M + 2E + 2e-3): slab center passing
// d_i <= D_i for all 4 planes => whole slab definitely inside (convexity,
// margin >= 2e-3 - eval_err ~ 1.8e-3 >> ref rounding shell; normal row and
// adjugate row are both 2*face-area so |det| cancels in barycentric units;
// degenerate facets have max interior distance ~0 and cannot pass).
// ---------------------------------------------------------------------------
__global__ __launch_bounds__(512) void precompute_kernel(
    const float* __restrict__ vertices,
    const int*   __restrict__ facets,
    float*       __restrict__ cul,
    float*       __restrict__ body)
{
    __shared__ unsigned skey[NFAC];
    const int b = blockIdx.x;
    const int j = threadIdx.x;          // one facet per thread
    const float* vb = vertices + (size_t)b * NVERT * 3;

    int4 fi = ((const int4*)facets)[b * NFAC + j];
    float x0 = vb[3*fi.x+0], y0 = vb[3*fi.x+1], z0 = vb[3*fi.x+2];
    float x1 = vb[3*fi.y+0], y1 = vb[3*fi.y+1], z1 = vb[3*fi.y+2];
    float x2 = vb[3*fi.z+0], y2 = vb[3*fi.z+1], z2 = vb[3*fi.z+2];
    float x3 = vb[3*fi.w+0], y3 = vb[3*fi.w+1], z3 = vb[3*fi.w+2];
    float a  = x0-x3, bb = x1-x3, c  = x2-x3;
    float d  = y0-y3, e  = y1-y3, f  = y2-y3;
    float g  = z0-z3, h  = z1-z3, ii = z2-z3;
    float A00 = e*ii - f*h,  A01 = c*h  - bb*ii, A02 = bb*f - c*e;
    float A10 = f*g  - d*ii, A11 = a*ii - c*g,   A12 = c*d  - a*f;
    float A20 = d*h  - e*g,  A21 = bb*g - a*h,   A22 = a*e  - bb*d;
    float det = a*(e*ii - f*h) - bb*(d*ii - f*g) + c*(d*h - e*g);
    if (det < 0.0f) {   // sign-fold (exact)
        det = -det;
        A00 = -A00; A01 = -A01; A02 = -A02;
        A10 = -A10; A11 = -A11; A12 = -A12;
        A20 = -A20; A21 = -A21; A22 = -A22;
    }
    unsigned myk = ~__float_as_uint(det);   // ascending key == descending |det|
    skey[j] = myk;
    __syncthreads();

    // rank = #{k : key_k < myk or (key_k == myk and k < j)}  -> unique slot
    int rank = 0;
    const uint4* sk4 = (const uint4*)skey;
    for (int k0 = 0; k0 < NFAC; k0 += 4) {
        uint4 kk = sk4[k0 >> 2];
        rank += (kk.x < myk) + ((kk.x == myk) & (k0 + 0 < j));
        rank += (kk.y < myk) + ((kk.y == myk) & (k0 + 1 < j));
        rank += (kk.z < myk) + ((kk.z == myk) & (k0 + 2 < j));
        rank += (kk.w < myk) + ((kk.w == myk) & (k0 + 3 < j));
    }

    CUL(0, b, rank) = fminf(fminf(x0,x1),fminf(x2,x3)) - 1e-4f;
    CUL(1, b, rank) = fminf(fminf(y0,y1),fminf(y2,y3)) - 1e-4f;
    CUL(2, b, rank) = fminf(fminf(z0,z1),fminf(z2,z3)) - 1e-4f;
    CUL(3, b, rank) = fmaxf(fmaxf(x0,x1),fmaxf(x2,x3)) + 1e-4f;
    CUL(4, b, rank) = fmaxf(fmaxf(y0,y1),fmaxf(y2,y3)) + 1e-4f;
    CUL(5, b, rank) = fmaxf(fmaxf(z0,z1),fmaxf(z2,z3)) + 1e-4f;

    // 4 outward face planes, margin-inflated, slab half-extents folded:
    // overlap test becomes  dot(n, slab_center) - rhs <= 0   (conservative).
    // containment test:     dot(n, slab_center) - rhs <= D   (definite).
    const float HX = 7.0f/96.0f, HZ = 3.0f/96.0f;
    auto plane = [&](float pax, float pay, float paz,
                     float pbx, float pby, float pbz,
                     float pcx, float pcy, float pcz,
                     float pox, float poy, float poz, int base, int pi) {
        float e1x = pbx-pax, e1y = pby-pay, e1z = pbz-paz;
        float e2x = pcx-pax, e2y = pcy-pay, e2z = pcz-paz;
        float nx = e1y*e2z - e1z*e2y;
        float ny = e1z*e2x - e1x*e2z;
        float nz = e1x*e2y - e1y*e2x;
        float sdot = nx*(pox-pax) + ny*(poy-pay) + nz*(poz-paz);
        if (sdot > 0.0f) { nx=-nx; ny=-ny; nz=-nz; sdot=-sdot; }
        float dpl = nx*pax + ny*pay + nz*paz;
        float n1s = fabsf(nx)+fabsf(ny)+fabsf(nz);
        float M = 1e-4f*(-sdot) + 1e-4f*n1s + 1e-4f;
        float E = fabsf(nx)*HX + fabsf(ny)*HX + fabsf(nz)*HZ;
        float rhs = dpl + M + E;
        CUL(base+0, b, rank) = nx;
        CUL(base+1, b, rank) = ny;
        CUL(base+2, b, rank) = nz;
        CUL(base+3, b, rank) = rhs;
        CUL(22+pi, b, rank) = -(M + 2.0f*E + 2e-3f);   // containment delta
    };
    plane(x1,y1,z1, x2,y2,z2, x3,y3,z3, x0,y0,z0, 6, 0);    // opposite v0
    plane(x0,y0,z0, x2,y2,z2, x3,y3,z3, x1,y1,z1, 10, 1);   // opposite v1
    plane(x0,y0,z0, x1,y1,z1, x3,y3,z3, x2,y2,z2, 14, 2);   // opposite v2
    plane(x0,y0,z0, x1,y1,z1, x2,y2,z2, x3,y3,z3, 18, 3);   // opposite v3

    float* bo = body + ((size_t)b * NFAC + rank) * RECF;
    bo[0]  = det; bo[1]  = x3;  bo[2]  = y3;  bo[3]  = z3;
    bo[4]  = A00; bo[5]  = A01; bo[6]  = A02; bo[7]  = A10;
    bo[8]  = A11; bo[9]  = A12; bo[10] = A20; bo[11] = A21;
    bo[12] = A22;
    bo[13] = det * (1.0f - 1e-5f) - 1e-25f;   // dhi
    bo[14] = det * (1.0f + 1e-5f) + 1e-25f;   // mhi
    bo[15] = 0.0f;
}

// ---------------------------------------------------------------------------
// Kernel 2: per-slab 512-bit facet mask + per-slab "fully contained" flag.
// One block per (batch, x-y column); facet-per-lane, cull record loaded ONCE
// (SoA, coalesced), 24 z-slabs via incremental plane dots (error ~1e-4 <<
// margins folded into rhs / delta).
// ---------------------------------------------------------------------------
__global__ __launch_bounds__(512) void mask_kernel(
    const float* __restrict__ cul,
    unsigned long long* __restrict__ masks,
    unsigned* __restrict__ fullmask)
{
    __shared__ unsigned fullbits;
    const int col = blockIdx.x;           // 0..143 = sx*12+sy
    const int b   = blockIdx.y;
    const int f   = threadIdx.x;          // facet (sorted order)
    const int w   = threadIdx.x >> 6;
    if (threadIdx.x == 0) fullbits = 0u;
    __syncthreads();
    float bminx=CUL(0,b,f), bminy=CUL(1,b,f), bminz=CUL(2,b,f);
    float bmaxx=CUL(3,b,f), bmaxy=CUL(4,b,f), bmaxz=CUL(5,b,f);
    float n0x=CUL(6,b,f),  n0y=CUL(7,b,f),  n0z=CUL(8,b,f),  r0=CUL(9,b,f);
    float n1x=CUL(10,b,f), n1y=CUL(11,b,f), n1z=CUL(12,b,f), r1=CUL(13,b,f);
    float n2x=CUL(14,b,f), n2y=CUL(15,b,f), n2z=CUL(16,b,f), r2=CUL(17,b,f);
    float n3x=CUL(18,b,f), n3y=CUL(19,b,f), n3z=CUL(20,b,f), r3=CUL(21,b,f);
    float D0=CUL(22,b,f), D1=CUL(23,b,f), D2=CUL(24,b,f), D3=CUL(25,b,f);

    const int sx = col / 12, sy = col % 12;
    const float cx = (float)(16*sx + 8 - VWD) / 96.0f;
    const float cy = (float)(16*sy + 8 - VWD) / 96.0f;
    const float colminx = (float)(16*sx + 1  - VWD) / 96.0f;
    const float colmaxx = (float)(16*sx + 15 - VWD) / 96.0f;
    const float colminy = (float)(16*sy + 1  - VWD) / 96.0f;
    const float colmaxy = (float)(16*sy + 15 - VWD) / 96.0f;
    const bool ovxy = (bminx <= colmaxx) & (bmaxx >= colminx) &
                      (bminy <= colmaxy) & (bmaxy >= colminy);

    const float cz0   = (float)(4 - VWD) / 96.0f;   // z-center of slab sz=0
    const float stepc = 8.0f / 96.0f;
    float d0 = n0x*cx + n0y*cy + n0z*cz0 - r0;  float s0 = n0z*stepc;
    float d1 = n1x*cx + n1y*cy + n1z*cz0 - r1;  float s1 = n1z*stepc;
    float d2 = n2x*cx + n2y*cy + n2z*cz0 - r2;  float s2 = n2z*stepc;
    float d3 = n3x*cx + n3y*cy + n3z*cz0 - r3;  float s3 = n3z*stepc;
    float zlo = (float)(1 - VWD) / 96.0f;
    float zhi = (float)(7 - VWD) / 96.0f;

    unsigned fullw = 0u;
    unsigned long long* mp = masks + ((size_t)b * NSLAB + (size_t)col * 24) * 8 + w;
#pragma unroll 4
    for (int sz = 0; sz < 24; ++sz) {
        bool ov = ovxy & (bminz <= zhi) & (bmaxz >= zlo) &
                  (d0 <= 0.0f) & (d1 <= 0.0f) & (d2 <= 0.0f) & (d3 <= 0.0f);
        bool fullv = (d0 <= D0) & (d1 <= D1) & (d2 <= D2) & (d3 <= D3);
        unsigned long long bal = __ballot((int)ov);
        if ((threadIdx.x & 63) == 0) mp[(size_t)sz * 8] = bal;
        if (__ballot((int)fullv) != 0ull) fullw |= (1u << sz);
        d0 += s0; d1 += s1; d2 += s2; d3 += s3;
        zlo += stepc; zhi += stepc;
    }
    if ((threadIdx.x & 63) == 0 && fullw) atomicOr(&fullbits, fullw);
    __syncthreads();
    if (threadIdx.x == 0) fullmask[b * 144 + col] = fullbits;
}

// ---------------------------------------------------------------------------
// Per-candidate exact test (shared by pass 1 and the straggler pass).
// Numerators bit-identical to ref; exact l_i>=0 sign test; det-relative shell
// on the sum; per-lane 4-bit `need` mask so only ONE __any branch per
// candidate guards the (rare) exact-division path.
// ---------------------------------------------------------------------------
__device__ __forceinline__ void facet_test(
    const float* __restrict__ bo,
    float px, float py, float pz0, float pz1, float pz2, float pz3,
    unsigned& fnd)
{
    float det = bo[0], v3x = bo[1], v3y = bo[2], v3z = bo[3];
    float A00 = bo[4],  A01 = bo[5],  A02 = bo[6],  A10 = bo[7];
    float A11 = bo[8],  A12 = bo[9],  A20 = bo[10], A21 = bo[11];
    float A22 = bo[12], dhi = bo[13], mhi = bo[14];
    float dx = px - v3x, dy = py - v3y;
    // ref-exact partials (left-assoc, contract off)
    float p0 = A00*dx + A01*dy;
    float p1 = A10*dx + A11*dy;
    float p2 = A20*dx + A21*dy;
    float dzk0 = pz0 - v3z, dzk1 = pz1 - v3z;
    float dzk2 = pz2 - v3z, dzk3 = pz3 - v3z;
    unsigned need = 0u;   // bit k: lane in shell, must run exact path
#pragma unroll
    for (int k = 0; k < 4; ++k) {
        float dzk = (k == 0) ? dzk0 : (k == 1) ? dzk1
                  : (k == 2) ? dzk2 : dzk3;
        // n_i bit-identical to reference's numerators
        float n0 = p0 + A02*dzk;
        float n1 = p1 + A12*dzk;
        float n2 = p2 + A22*dzk;
        float sm = (n0 + n1) + n2;
        float mn = fminf(fminf(n0, n1), n2);   // v_min3_f32
        bool ge0 = (mn >= 0.0f);               // EXACT l_i>=0 test
        bool def = ge0 & (sm <= dhi);
        bool may = ge0 & (sm <= mhi);
        if (may & !def & !((fnd >> k) & 1u)) need |= (1u << k);
        if (def) fnd |= (1u << k);
    }
    if (__any(need != 0u)) {
        // exact path (rare): ref's divisions + final test, per k
#pragma unroll
        for (int k = 0; k < 4; ++k) {
            float dzk = (k == 0) ? dzk0 : (k == 1) ? dzk1
                      : (k == 2) ? dzk2 : dzk3;
            float n0 = p0 + A02*dzk;
            float n1 = p1 + A12*dzk;
            float n2 = p2 + A22*dzk;
            float l0 = n0 / det;
            float l1 = n1 / det;
            float l2 = n2 / det;
            float l3 = 1.0f - ((l0 + l1) + l2);
            bool inside = (l0 >= 0.0f) & (l0 <= 1.0f) &
                          (l1 >= 0.0f) & (l1 <= 1.0f) &
                          (l2 >= 0.0f) & (l2 <= 1.0f) &
                          (l3 >= 0.0f) & (l3 <= 1.0f);
            if (((need >> k) & 1u) & inside) fnd |= (1u << k);
        }
    }
}

// ---------------------------------------------------------------------------
// Kernel 3 (pass 1): 2-WAVE blocks. Fully-contained slabs (fullmask bit)
// write 1s with NO scanning; candidate scan capped at mask words 0..1 (128
// biggest-|det| facets). Incomplete waves with work left in words 2..7 set a
// per-slab FLAG BYTE (distinct addresses -> NO atomics; every wave writes its
// own flag unconditionally so no zeroing / stale data). R1 lesson: the
// single-dword atomicAdd straggler list serialized ~16k waves through one L2
// bank (198us wall, 8% VALU, 70% occupancy).
// ---------------------------------------------------------------------------
__global__ __launch_bounds__(128) void voxelize_kernel(
    const float*              __restrict__ body,
    const unsigned long long* __restrict__ masks,
    const unsigned*           __restrict__ fullmask,
    float*                    __restrict__ out,
    unsigned char*            __restrict__ needf)
{
    const int b    = blockIdx.y;
    const int wave = threadIdx.x >> 6;
    const int lane = threadIdx.x & 63;
    const int slab = blockIdx.x * 2 + wave;          // 0 .. 3455
    const int sz = slab % 24;
    const int col = slab / 24;
    const int sy = col % 12;
    const int sx = slab / 288;
    const int ix  = sx*8 + (lane >> 3);
    const int iy  = sy*8 + (lane & 7);
    const int iz0 = sz*4;

    const float px  = (float)(2*ix + 1 - VWD) / 96.0f;
    const float py  = (float)(2*iy + 1 - VWD) / 96.0f;
    const float pz0 = (float)(2*(iz0+0) + 1 - VWD) / 96.0f;
    const float pz1 = (float)(2*(iz0+1) + 1 - VWD) / 96.0f;
    const float pz2 = (float)(2*(iz0+2) + 1 - VWD) / 96.0f;
    const float pz3 = (float)(2*(iz0+3) + 1 - VWD) / 96.0f;

    unsigned fnd = 0u;   // bit k = voxel (ix,iy,iz0+k) found
    bool push = false;

    // fully-contained slab: convexity => every voxel definitely inside.
    if ((fullmask[b * 144 + col] >> sz) & 1u) { fnd = 15u; goto done; }

    {
        const unsigned long long* mp = masks + ((size_t)b * NSLAB + slab) * 8;
        const float* bb = body + (size_t)b * NFAC * RECF;
#pragma unroll
        for (int w = 0; w < 2; ++w) {
            unsigned long long m = mp[w];   // wave-uniform -> SGPR
            while (m) {
                int bit = __builtin_ctzll(m);
                m &= m - 1;
                int f = __builtin_amdgcn_readfirstlane(w * 64 + bit);
                facet_test(bb + f * RECF, px, py, pz0, pz1, pz2, pz3, fnd);
                if (__all(fnd == 15u)) goto done;
            }
        }
        // cap reached: defer remaining words to the straggler pass
        unsigned long long rem = mp[2] | mp[3] | mp[4] | mp[5] | mp[6] | mp[7];
        push = (rem != 0ull) && !__all(fnd == 15u);
    }
done:
    if (lane == 0) needf[(size_t)b * NSLAB + slab] = push ? 1 : 0;
    float4 v;
    v.x = (fnd & 1u) ? 1.0f : 0.0f;
    v.y = (fnd & 2u) ? 1.0f : 0.0f;
    v.z = (fnd & 4u) ? 1.0f : 0.0f;
    v.w = (fnd & 8u) ? 1.0f : 0.0f;
    *(float4*)&out[(size_t)b*(VWD*VWD*VWD) + (size_t)ix*(VWD*VWD) + iy*VWD + iz0] = v;
}

// ---------------------------------------------------------------------------
// Kernel 4 (pass 2, stragglers only): one block per (slab, batch); blocks
// with a clear flag read one scalar byte and retire. Flagged blocks run 6
// waves, wave w scanning mask word 2+w, seeded with pass-1 partial result
// from `out`; per-lane union in LDS gives cross-wave early exit.
// ---------------------------------------------------------------------------
__global__ __launch_bounds__(384) void voxelize_fix_kernel(
    const float*              __restrict__ body,
    const unsigned long long* __restrict__ masks,
    float*                    __restrict__ out,
    const unsigned char*      __restrict__ needf)
{
    __shared__ unsigned fl[64];
    const int slab = blockIdx.x;
    const int b    = blockIdx.y;
    if (!needf[(size_t)b * NSLAB + slab]) return;   // block-uniform

    const int wave = threadIdx.x >> 6;          // 0..5 -> words 2..7
    const int lane = threadIdx.x & 63;
    const int sz = slab % 24;
    const int sy = (slab / 24) % 12;
    const int sx = slab / 288;
    const int ix  = sx*8 + (lane >> 3);
    const int iy  = sy*8 + (lane & 7);
    const int iz0 = sz*4;
    const float px  = (float)(2*ix + 1 - VWD) / 96.0f;
    const float py  = (float)(2*iy + 1 - VWD) / 96.0f;
    const float pz0 = (float)(2*(iz0+0) + 1 - VWD) / 96.0f;
    const float pz1 = (float)(2*(iz0+1) + 1 - VWD) / 96.0f;
    const float pz2 = (float)(2*(iz0+2) + 1 - VWD) / 96.0f;
    const float pz3 = (float)(2*(iz0+3) + 1 - VWD) / 96.0f;
    float* op = &out[(size_t)b*(VWD*VWD*VWD) + (size_t)ix*(VWD*VWD) + iy*VWD + iz0];

    if (threadIdx.x < 64) {
        float4 o = *(const float4*)op;
        fl[threadIdx.x] = (o.x != 0.0f ? 1u : 0u) | (o.y != 0.0f ? 2u : 0u)
                        | (o.z != 0.0f ? 4u : 0u) | (o.w != 0.0f ? 8u : 0u);
    }
    __syncthreads();

    unsigned fnd = fl[lane];          // seed from pass-1 partial
    unsigned pub = fnd;
    const unsigned long long* mp = masks + ((size_t)b * NSLAB + slab) * 8;
    const float* bb = body + (size_t)b * NFAC * RECF;
    unsigned long long m = mp[2 + wave];
    while (m) {
        int bit = __builtin_ctzll(m);
        m &= m - 1;
        int f = __builtin_amdgcn_readfirstlane((2 + wave) * 64 + bit);
        facet_test(bb + f * RECF, px, py, pz0, pz1, pz2, pz3, fnd);
        if (fnd != pub) { atomicOr(&fl[lane], fnd); pub = fnd; }
        fnd |= fl[lane];              // cross-wave union (monotonic)
        if (__all(fnd == 15u)) break;
    }
    if (fnd != pub) atomicOr(&fl[lane], fnd);
    __syncthreads();
    if (threadIdx.x < 64) {
        unsigned u = fl[threadIdx.x];
        float4 r;
        r.x = (u & 1u) ? 1.0f : 0.0f;
        r.y = (u & 2u) ? 1.0f : 0.0f;
        r.z = (u & 4u) ? 1.0f : 0.0f;
        r.w = (u & 8u) ? 1.0f : 0.0f;
        *(float4*)op = r;
    }
}

extern "C" void kernel_launch(void* const* d_in, const int* in_sizes, int n_in,
                              void* d_out, int out_size, void* d_ws, size_t ws_size,
                              hipStream_t stream) {
    const float* vertices = (const float*)d_in[0];   // (8, 2048, 3) f32
    const int*   facets   = (const int*)d_in[1];     // (8, 512, 4) int
    float*       out      = (float*)d_out;           // (8, 96, 96, 96) f32

    // d_ws layout:
    //   cul SoA     26*8*512*4 = 425984   @ 0
    //   body        8*512*16*4 = 262144   @ 425984
    //   masks       8*3456*8*8 = 1769472  @ 688128
    //   fullmask    8*144*4    = 4608     @ 2457600
    //   needf       8*3456     = 27648    @ 2462208   (end ~2.49 MB)
    float* cul  = (float*)d_ws;
    float* body = (float*)((char*)d_ws + 425984);
    unsigned long long* msk = (unsigned long long*)((char*)d_ws + 688128);
    unsigned* fullmask = (unsigned*)((char*)d_ws + 2457600);
    unsigned char* needf = (unsigned char*)((char*)d_ws + 2462208);

    precompute_kernel<<<NBATCH, 512, 0, stream>>>(vertices, facets, cul, body);
    mask_kernel<<<dim3(144, NBATCH), 512, 0, stream>>>(cul, msk, fullmask);
    dim3 grid(NSLAB / 2, NBATCH);   // 1728 blocks x 2 waves = 3456 slabs/batch
    voxelize_kernel<<<grid, 128, 0, stream>>>(body, msk, fullmask, out, needf);
    voxelize_fix_kernel<<<dim3(NSLAB, NBATCH), 384, 0, stream>>>(body, msk, out, needf);
}

// Round 3
// 175.610 us; speedup vs baseline: 2.0447x; 1.0384x over previous
//
#include <hip/hip_runtime.h>

// Match numpy f32 semantics: no FMA contraction anywhere in this TU.
#pragma clang fp contract(off)

#define VWD 96
#define NVERT 2048
#define NFAC 512
#define NBATCH 8
#define NSLAB 3456          // 12 x 12 x 24 slabs of 8x8x4 voxels
#define RECF 16             // floats per facet body record
#define CULC 26             // cull components (SoA): bbox 6 + 4 planes x 4 + 4 containment deltas

// SoA cull addressing: component c, batch b, facet f
#define CUL(c, b, f) cul[(size_t)(c) * (NBATCH * NFAC) + (size_t)(b) * NFAC + (f)]

// ---------------------------------------------------------------------------
// Kernel 1: per-batch facet precompute, ordered by |det| descending via a
// ONE-BARRIER rank sort. Fully scalarized. Body records SIGN-FOLDED: det<0 =>
// negate A,det (IEEE negation commutes exactly through mul/add/div, so
// n'/det' == n/det bit-for-bit).
//   body[b][s][16] : det,v3x,v3y,v3z, A00..A22, dhi, mhi, pad
//   dhi = det*(1-1e-5) - 1e-25   (definite-inside upper bound on sum)
//   mhi = det*(1+1e-5) + 1e-25   (maybe-inside upper bound; +-1e-25 guards
//                                 det=0 degenerate facets: ref l=NaN=outside)
// Per-plane containment delta D_i = -(M + 2E + 2e-3): slab center passing
// d_i <= D_i for all 4 planes => whole slab definitely inside (convexity,
// margin >= 2e-3 - eval_err ~ 1.8e-3 >> ref rounding shell; normal row and
// adjugate row are both 2*face-area so |det| cancels in barycentric units;
// degenerate facets have max interior distance ~0 and cannot pass).
// ---------------------------------------------------------------------------
__global__ __launch_bounds__(512) void precompute_kernel(
    const float* __restrict__ vertices,
    const int*   __restrict__ facets,
    float*       __restrict__ cul,
    float*       __restrict__ body)
{
    __shared__ unsigned skey[NFAC];
    const int b = blockIdx.x;
    const int j = threadIdx.x;          // one facet per thread
    const float* vb = vertices + (size_t)b * NVERT * 3;

    int4 fi = ((const int4*)facets)[b * NFAC + j];
    float x0 = vb[3*fi.x+0], y0 = vb[3*fi.x+1], z0 = vb[3*fi.x+2];
    float x1 = vb[3*fi.y+0], y1 = vb[3*fi.y+1], z1 = vb[3*fi.y+2];
    float x2 = vb[3*fi.z+0], y2 = vb[3*fi.z+1], z2 = vb[3*fi.z+2];
    float x3 = vb[3*fi.w+0], y3 = vb[3*fi.w+1], z3 = vb[3*fi.w+2];
    float a  = x0-x3, bb = x1-x3, c  = x2-x3;
    float d  = y0-y3, e  = y1-y3, f  = y2-y3;
    float g  = z0-z3, h  = z1-z3, ii = z2-z3;
    float A00 = e*ii - f*h,  A01 = c*h  - bb*ii, A02 = bb*f - c*e;
    float A10 = f*g  - d*ii, A11 = a*ii - c*g,   A12 = c*d  - a*f;
    float A20 = d*h  - e*g,  A21 = bb*g - a*h,   A22 = a*e  - bb*d;
    float det = a*(e*ii - f*h) - bb*(d*ii - f*g) + c*(d*h - e*g);
    if (det < 0.0f) {   // sign-fold (exact)
        det = -det;
        A00 = -A00; A01 = -A01; A02 = -A02;
        A10 = -A10; A11 = -A11; A12 = -A12;
        A20 = -A20; A21 = -A21; A22 = -A22;
    }
    unsigned myk = ~__float_as_uint(det);   // ascending key == descending |det|
    skey[j] = myk;
    __syncthreads();

    // rank = #{k : key_k < myk or (key_k == myk and k < j)}  -> unique slot
    int rank = 0;
    const uint4* sk4 = (const uint4*)skey;
    for (int k0 = 0; k0 < NFAC; k0 += 4) {
        uint4 kk = sk4[k0 >> 2];
        rank += (kk.x < myk) + ((kk.x == myk) & (k0 + 0 < j));
        rank += (kk.y < myk) + ((kk.y == myk) & (k0 + 1 < j));
        rank += (kk.z < myk) + ((kk.z == myk) & (k0 + 2 < j));
        rank += (kk.w < myk) + ((kk.w == myk) & (k0 + 3 < j));
    }

    CUL(0, b, rank) = fminf(fminf(x0,x1),fminf(x2,x3)) - 1e-4f;
    CUL(1, b, rank) = fminf(fminf(y0,y1),fminf(y2,y3)) - 1e-4f;
    CUL(2, b, rank) = fminf(fminf(z0,z1),fminf(z2,z3)) - 1e-4f;
    CUL(3, b, rank) = fmaxf(fmaxf(x0,x1),fmaxf(x2,x3)) + 1e-4f;
    CUL(4, b, rank) = fmaxf(fmaxf(y0,y1),fmaxf(y2,y3)) + 1e-4f;
    CUL(5, b, rank) = fmaxf(fmaxf(z0,z1),fmaxf(z2,z3)) + 1e-4f;

    // 4 outward face planes, margin-inflated, slab half-extents folded:
    // overlap test becomes  dot(n, slab_center) - rhs <= 0   (conservative).
    // containment test:     dot(n, slab_center) - rhs <= D   (definite).
    const float HX = 7.0f/96.0f, HZ = 3.0f/96.0f;
    auto plane = [&](float pax, float pay, float paz,
                     float pbx, float pby, float pbz,
                     float pcx, float pcy, float pcz,
                     float pox, float poy, float poz, int base, int pi) {
        float e1x = pbx-pax, e1y = pby-pay, e1z = pbz-paz;
        float e2x = pcx-pax, e2y = pcy-pay, e2z = pcz-paz;
        float nx = e1y*e2z - e1z*e2y;
        float ny = e1z*e2x - e1x*e2z;
        float nz = e1x*e2y - e1y*e2x;
        float sdot = nx*(pox-pax) + ny*(poy-pay) + nz*(poz-paz);
        if (sdot > 0.0f) { nx=-nx; ny=-ny; nz=-nz; sdot=-sdot; }
        float dpl = nx*pax + ny*pay + nz*paz;
        float n1s = fabsf(nx)+fabsf(ny)+fabsf(nz);
        float M = 1e-4f*(-sdot) + 1e-4f*n1s + 1e-4f;
        float E = fabsf(nx)*HX + fabsf(ny)*HX + fabsf(nz)*HZ;
        float rhs = dpl + M + E;
        CUL(base+0, b, rank) = nx;
        CUL(base+1, b, rank) = ny;
        CUL(base+2, b, rank) = nz;
        CUL(base+3, b, rank) = rhs;
        CUL(22+pi, b, rank) = -(M + 2.0f*E + 2e-3f);   // containment delta
    };
    plane(x1,y1,z1, x2,y2,z2, x3,y3,z3, x0,y0,z0, 6, 0);    // opposite v0
    plane(x0,y0,z0, x2,y2,z2, x3,y3,z3, x1,y1,z1, 10, 1);   // opposite v1
    plane(x0,y0,z0, x1,y1,z1, x3,y3,z3, x2,y2,z2, 14, 2);   // opposite v2
    plane(x0,y0,z0, x1,y1,z1, x2,y2,z2, x3,y3,z3, 18, 3);   // opposite v3

    float* bo = body + ((size_t)b * NFAC + rank) * RECF;
    bo[0]  = det; bo[1]  = x3;  bo[2]  = y3;  bo[3]  = z3;
    bo[4]  = A00; bo[5]  = A01; bo[6]  = A02; bo[7]  = A10;
    bo[8]  = A11; bo[9]  = A12; bo[10] = A20; bo[11] = A21;
    bo[12] = A22;
    bo[13] = det * (1.0f - 1e-5f) - 1e-25f;   // dhi
    bo[14] = det * (1.0f + 1e-5f) + 1e-25f;   // mhi
    bo[15] = 0.0f;
}

// ---------------------------------------------------------------------------
// Kernel 2: per-slab 512-bit facet mask + per-slab "fully contained" flag.
// One block per (batch, x-y column); facet-per-lane, cull record loaded ONCE
// (SoA, coalesced), 24 z-slabs via incremental plane dots (error ~1e-4 <<
// margins folded into rhs / delta).
// ---------------------------------------------------------------------------
__global__ __launch_bounds__(512) void mask_kernel(
    const float* __restrict__ cul,
    unsigned long long* __restrict__ masks,
    unsigned* __restrict__ fullmask)
{
    __shared__ unsigned fullbits;
    const int col = blockIdx.x;           // 0..143 = sx*12+sy
    const int b   = blockIdx.y;
    const int f   = threadIdx.x;          // facet (sorted order)
    const int w   = threadIdx.x >> 6;
    if (threadIdx.x == 0) fullbits = 0u;
    __syncthreads();
    float bminx=CUL(0,b,f), bminy=CUL(1,b,f), bminz=CUL(2,b,f);
    float bmaxx=CUL(3,b,f), bmaxy=CUL(4,b,f), bmaxz=CUL(5,b,f);
    float n0x=CUL(6,b,f),  n0y=CUL(7,b,f),  n0z=CUL(8,b,f),  r0=CUL(9,b,f);
    float n1x=CUL(10,b,f), n1y=CUL(11,b,f), n1z=CUL(12,b,f), r1=CUL(13,b,f);
    float n2x=CUL(14,b,f), n2y=CUL(15,b,f), n2z=CUL(16,b,f), r2=CUL(17,b,f);
    float n3x=CUL(18,b,f), n3y=CUL(19,b,f), n3z=CUL(20,b,f), r3=CUL(21,b,f);
    float D0=CUL(22,b,f), D1=CUL(23,b,f), D2=CUL(24,b,f), D3=CUL(25,b,f);

    const int sx = col / 12, sy = col % 12;
    const float cx = (float)(16*sx + 8 - VWD) / 96.0f;
    const float cy = (float)(16*sy + 8 - VWD) / 96.0f;
    const float colminx = (float)(16*sx + 1  - VWD) / 96.0f;
    const float colmaxx = (float)(16*sx + 15 - VWD) / 96.0f;
    const float colminy = (float)(16*sy + 1  - VWD) / 96.0f;
    const float colmaxy = (float)(16*sy + 15 - VWD) / 96.0f;
    const bool ovxy = (bminx <= colmaxx) & (bmaxx >= colminx) &
                      (bminy <= colmaxy) & (bmaxy >= colminy);

    const float cz0   = (float)(4 - VWD) / 96.0f;   // z-center of slab sz=0
    const float stepc = 8.0f / 96.0f;
    float d0 = n0x*cx + n0y*cy + n0z*cz0 - r0;  float s0 = n0z*stepc;
    float d1 = n1x*cx + n1y*cy + n1z*cz0 - r1;  float s1 = n1z*stepc;
    float d2 = n2x*cx + n2y*cy + n2z*cz0 - r2;  float s2 = n2z*stepc;
    float d3 = n3x*cx + n3y*cy + n3z*cz0 - r3;  float s3 = n3z*stepc;
    float zlo = (float)(1 - VWD) / 96.0f;
    float zhi = (float)(7 - VWD) / 96.0f;

    unsigned fullw = 0u;
    unsigned long long* mp = masks + ((size_t)b * NSLAB + (size_t)col * 24) * 8 + w;
#pragma unroll 4
    for (int sz = 0; sz < 24; ++sz) {
        bool ov = ovxy & (bminz <= zhi) & (bmaxz >= zlo) &
                  (d0 <= 0.0f) & (d1 <= 0.0f) & (d2 <= 0.0f) & (d3 <= 0.0f);
        bool fullv = (d0 <= D0) & (d1 <= D1) & (d2 <= D2) & (d3 <= D3);
        unsigned long long bal = __ballot((int)ov);
        if ((threadIdx.x & 63) == 0) mp[(size_t)sz * 8] = bal;
        if (__ballot((int)fullv) != 0ull) fullw |= (1u << sz);
        d0 += s0; d1 += s1; d2 += s2; d3 += s3;
        zlo += stepc; zhi += stepc;
    }
    if ((threadIdx.x & 63) == 0 && fullw) atomicOr(&fullbits, fullw);
    __syncthreads();
    if (threadIdx.x == 0) fullmask[b * 144 + col] = fullbits;
}

// ---------------------------------------------------------------------------
// Per-candidate exact test (shared by pass 1 and the straggler pass).
// Numerators bit-identical to ref; exact l_i>=0 sign test; det-relative shell
// on the sum; per-lane 4-bit `need` mask so only ONE __any branch per
// candidate guards the (rare) exact-division path.
// ---------------------------------------------------------------------------
__device__ __forceinline__ void facet_test(
    const float* __restrict__ bo,
    float px, float py, float pz0, float pz1, float pz2, float pz3,
    unsigned& fnd)
{
    float det = bo[0], v3x = bo[1], v3y = bo[2], v3z = bo[3];
    float A00 = bo[4],  A01 = bo[5],  A02 = bo[6],  A10 = bo[7];
    float A11 = bo[8],  A12 = bo[9],  A20 = bo[10], A21 = bo[11];
    float A22 = bo[12], dhi = bo[13], mhi = bo[14];
    float dx = px - v3x, dy = py - v3y;
    // ref-exact partials (left-assoc, contract off)
    float p0 = A00*dx + A01*dy;
    float p1 = A10*dx + A11*dy;
    float p2 = A20*dx + A21*dy;
    float dzk0 = pz0 - v3z, dzk1 = pz1 - v3z;
    float dzk2 = pz2 - v3z, dzk3 = pz3 - v3z;
    unsigned need = 0u;   // bit k: lane in shell, must run exact path
#pragma unroll
    for (int k = 0; k < 4; ++k) {
        float dzk = (k == 0) ? dzk0 : (k == 1) ? dzk1
                  : (k == 2) ? dzk2 : dzk3;
        // n_i bit-identical to reference's numerators
        float n0 = p0 + A02*dzk;
        float n1 = p1 + A12*dzk;
        float n2 = p2 + A22*dzk;
        float sm = (n0 + n1) + n2;
        float mn = fminf(fminf(n0, n1), n2);   // v_min3_f32
        bool ge0 = (mn >= 0.0f);               // EXACT l_i>=0 test
        bool def = ge0 & (sm <= dhi);
        bool may = ge0 & (sm <= mhi);
        if (may & !def & !((fnd >> k) & 1u)) need |= (1u << k);
        if (def) fnd |= (1u << k);
    }
    if (__any(need != 0u)) {
        // exact path (rare): ref's divisions + final test, per k
#pragma unroll
        for (int k = 0; k < 4; ++k) {
            float dzk = (k == 0) ? dzk0 : (k == 1) ? dzk1
                      : (k == 2) ? dzk2 : dzk3;
            float n0 = p0 + A02*dzk;
            float n1 = p1 + A12*dzk;
            float n2 = p2 + A22*dzk;
            float l0 = n0 / det;
            float l1 = n1 / det;
            float l2 = n2 / det;
            float l3 = 1.0f - ((l0 + l1) + l2);
            bool inside = (l0 >= 0.0f) & (l0 <= 1.0f) &
                          (l1 >= 0.0f) & (l1 <= 1.0f) &
                          (l2 >= 0.0f) & (l2 <= 1.0f) &
                          (l3 >= 0.0f) & (l3 <= 1.0f);
            if (((need >> k) & 1u) & inside) fnd |= (1u << k);
        }
    }
}

// ---------------------------------------------------------------------------
// Kernel 3 (pass 1): 2-WAVE blocks. Fully-contained slabs (fullmask bit)
// write 1s with NO scanning; candidate scan capped at mask words 0..1 (128
// biggest-|det| facets). Incomplete waves with work left in words 2..7 write
// a coalesced 64-byte PARTIAL record (4 bits/lane) + flag byte and SKIP the
// out write (pass 2 owns those voxels). R2 lesson: the out read-back in
// pass 2 cost ~60 MB HBM fetch (16B-of-64B-sector scatter, duplicated
// across XCDs); each out voxel is now written exactly once, read never.
// Block->slab mapping swizzled so the 4 consecutive-sz slabs that share a
// 64B out sector land on the SAME XCD (fine-grained round-robin otherwise).
// ---------------------------------------------------------------------------
__global__ __launch_bounds__(128) void voxelize_kernel(
    const float*              __restrict__ body,
    const unsigned long long* __restrict__ masks,
    const unsigned*           __restrict__ fullmask,
    float*                    __restrict__ out,
    unsigned char*            __restrict__ needf,
    unsigned char*            __restrict__ pfnd)
{
    const int b    = blockIdx.y;
    const int wave = threadIdx.x >> 6;
    const int lane = threadIdx.x & 63;
    // XCD sector swizzle: XCD x (= linear block % 8) gets pair {2x,2x+1} of
    // each 16-pair group -> slabs 4x..4x+3 = one 64B-sector of out.
    const int B    = blockIdx.x;                    // 0..1727
    const int pr   = B & 15;
    const int pair = (B >> 4) * 16 + (pr & 7) * 2 + (pr >> 3);
    const int slab = pair * 2 + wave;               // 0 .. 3455
    const int sz = slab % 24;
    const int col = slab / 24;
    const int sy = col % 12;
    const int sx = slab / 288;
    const int ix  = sx*8 + (lane >> 3);
    const int iy  = sy*8 + (lane & 7);
    const int iz0 = sz*4;

    const float px  = (float)(2*ix + 1 - VWD) / 96.0f;
    const float py  = (float)(2*iy + 1 - VWD) / 96.0f;
    const float pz0 = (float)(2*(iz0+0) + 1 - VWD) / 96.0f;
    const float pz1 = (float)(2*(iz0+1) + 1 - VWD) / 96.0f;
    const float pz2 = (float)(2*(iz0+2) + 1 - VWD) / 96.0f;
    const float pz3 = (float)(2*(iz0+3) + 1 - VWD) / 96.0f;

    unsigned fnd = 0u;   // bit k = voxel (ix,iy,iz0+k) found
    bool push = false;

    // fully-contained slab: convexity => every voxel definitely inside.
    if ((fullmask[b * 144 + col] >> sz) & 1u) { fnd = 15u; goto done; }

    {
        const unsigned long long* mp = masks + ((size_t)b * NSLAB + slab) * 8;
        const float* bb = body + (size_t)b * NFAC * RECF;
#pragma unroll
        for (int w = 0; w < 2; ++w) {
            unsigned long long m = mp[w];   // wave-uniform -> SGPR
            while (m) {
                int bit = __builtin_ctzll(m);
                m &= m - 1;
                int f = __builtin_amdgcn_readfirstlane(w * 64 + bit);
                facet_test(bb + f * RECF, px, py, pz0, pz1, pz2, pz3, fnd);
                if (__all(fnd == 15u)) goto done;
            }
        }
        // cap reached: defer remaining words to the straggler pass
        unsigned long long rem = mp[2] | mp[3] | mp[4] | mp[5] | mp[6] | mp[7];
        push = (rem != 0ull) && !__all(fnd == 15u);
    }
done:
    if (push) {
        // pass 2 owns this slab: hand off 4-bit partial per lane (64B/wave,
        // coalesced) and set the flag. No out write here.
        pfnd[((size_t)b * NSLAB + slab) * 64 + lane] = (unsigned char)fnd;
        if (lane == 0) needf[(size_t)b * NSLAB + slab] = 1;
    } else {
        if (lane == 0) needf[(size_t)b * NSLAB + slab] = 0;
        float4 v;
        v.x = (fnd & 1u) ? 1.0f : 0.0f;
        v.y = (fnd & 2u) ? 1.0f : 0.0f;
        v.z = (fnd & 4u) ? 1.0f : 0.0f;
        v.w = (fnd & 8u) ? 1.0f : 0.0f;
        *(float4*)&out[(size_t)b*(VWD*VWD*VWD) + (size_t)ix*(VWD*VWD) + iy*VWD + iz0] = v;
    }
}

// ---------------------------------------------------------------------------
// Kernel 4 (pass 2, stragglers only): one block per (slab, batch); blocks
// with a clear flag read one scalar byte and retire. Flagged blocks run 6
// waves, wave w scanning mask word 2+w, seeded from the 64B partial record
// (NOT from out); per-lane union in LDS gives cross-wave early exit; the
// block writes out at the end (sole writer of these voxels).
// Same XCD sector swizzle as pass 1.
// ---------------------------------------------------------------------------
__global__ __launch_bounds__(384) void voxelize_fix_kernel(
    const float*              __restrict__ body,
    const unsigned long long* __restrict__ masks,
    float*                    __restrict__ out,
    const unsigned char*      __restrict__ needf,
    const unsigned char*      __restrict__ pfnd)
{
    __shared__ unsigned fl[64];
    const int B = blockIdx.x;                       // 0..3455
    const int r = B & 31;
    const int slab = (B >> 5) * 32 + (r & 7) * 4 + (r >> 3);
    const int b    = blockIdx.y;
    if (!needf[(size_t)b * NSLAB + slab]) return;   // block-uniform

    const int wave = threadIdx.x >> 6;          // 0..5 -> words 2..7
    const int lane = threadIdx.x & 63;
    const int sz = slab % 24;
    const int sy = (slab / 24) % 12;
    const int sx = slab / 288;
    const int ix  = sx*8 + (lane >> 3);
    const int iy  = sy*8 + (lane & 7);
    const int iz0 = sz*4;
    const float px  = (float)(2*ix + 1 - VWD) / 96.0f;
    const float py  = (float)(2*iy + 1 - VWD) / 96.0f;
    const float pz0 = (float)(2*(iz0+0) + 1 - VWD) / 96.0f;
    const float pz1 = (float)(2*(iz0+1) + 1 - VWD) / 96.0f;
    const float pz2 = (float)(2*(iz0+2) + 1 - VWD) / 96.0f;
    const float pz3 = (float)(2*(iz0+3) + 1 - VWD) / 96.0f;

    if (threadIdx.x < 64)
        fl[threadIdx.x] = pfnd[((size_t)b * NSLAB + slab) * 64 + threadIdx.x];
    __syncthreads();

    unsigned fnd = fl[lane];          // seed from pass-1 partial
    unsigned pub = fnd;
    const unsigned long long* mp = masks + ((size_t)b * NSLAB + slab) * 8;
    const float* bb = body + (size_t)b * NFAC * RECF;
    unsigned long long m = mp[2 + wave];
    while (m) {
        int bit = __builtin_ctzll(m);
        m &= m - 1;
        int f = __builtin_amdgcn_readfirstlane((2 + wave) * 64 + bit);
        facet_test(bb + f * RECF, px, py, pz0, pz1, pz2, pz3, fnd);
        if (fnd != pub) { atomicOr(&fl[lane], fnd); pub = fnd; }
        fnd |= fl[lane];              // cross-wave union (monotonic)
        if (__all(fnd == 15u)) break;
    }
    if (fnd != pub) atomicOr(&fl[lane], fnd);
    __syncthreads();
    if (threadIdx.x < 64) {
        unsigned u = fl[threadIdx.x];
        float4 rv;
        rv.x = (u & 1u) ? 1.0f : 0.0f;
        rv.y = (u & 2u) ? 1.0f : 0.0f;
        rv.z = (u & 4u) ? 1.0f : 0.0f;
        rv.w = (u & 8u) ? 1.0f : 0.0f;
        *(float4*)&out[(size_t)b*(VWD*VWD*VWD) + (size_t)ix*(VWD*VWD) + iy*VWD + iz0] = rv;
    }
}

extern "C" void kernel_launch(void* const* d_in, const int* in_sizes, int n_in,
                              void* d_out, int out_size, void* d_ws, size_t ws_size,
                              hipStream_t stream) {
    const float* vertices = (const float*)d_in[0];   // (8, 2048, 3) f32
    const int*   facets   = (const int*)d_in[1];     // (8, 512, 4) int
    float*       out      = (float*)d_out;           // (8, 96, 96, 96) f32

    // d_ws layout:
    //   cul SoA     26*8*512*4 = 425984   @ 0
    //   body        8*512*16*4 = 262144   @ 425984
    //   masks       8*3456*8*8 = 1769472  @ 688128
    //   fullmask    8*144*4    = 4608     @ 2457600
    //   needf       8*3456     = 27648    @ 2462208
    //   pfnd        8*3456*64  = 1769472  @ 2489856   (end ~4.26 MB)
    float* cul  = (float*)d_ws;
    float* body = (float*)((char*)d_ws + 425984);
    unsigned long long* msk = (unsigned long long*)((char*)d_ws + 688128);
    unsigned* fullmask = (unsigned*)((char*)d_ws + 2457600);
    unsigned char* needf = (unsigned char*)((char*)d_ws + 2462208);
    unsigned char* pfnd  = (unsigned char*)((char*)d_ws + 2489856);

    precompute_kernel<<<NBATCH, 512, 0, stream>>>(vertices, facets, cul, body);
    mask_kernel<<<dim3(144, NBATCH), 512, 0, stream>>>(cul, msk, fullmask);
    dim3 grid(NSLAB / 2, NBATCH);   // 1728 blocks x 2 waves = 3456 slabs/batch
    voxelize_kernel<<<grid, 128, 0, stream>>>(body, msk, fullmask, out, needf, pfnd);
    voxelize_fix_kernel<<<dim3(NSLAB, NBATCH), 384, 0, stream>>>(body, msk, out, needf, pfnd);
}